// Round 1
// baseline (376.737 us; speedup 1.0000x reference)
//
#include <hip/hip_runtime.h>
#include <hip/hip_bf16.h>

#define BSZ 4
#define SEQ 48
#define DMODEL 256
#define NHEAD 2
#define HD 128
#define NLAYERS 2
#define DFF_C 2048
#define NQ_C 512
#define NV 1176                 /* valid spans per batch: 48*49/2 */
#define NTOT (BSZ * NV)         /* 4704 */
#define NTOTP 4736              /* NTOT padded to 128 multiple (37*128) */
#define NVP 1216                /* NV padded to 64 multiple (19*64) */
#define KSPLIT 5                /* key splits for flash-decoding */
#define SCALE 0.088388347648318447f   /* 1/sqrt(128) */

typedef unsigned short u16;
typedef __attribute__((ext_vector_type(8))) short bf16x8;
typedef __attribute__((ext_vector_type(4))) float f32x4;

__device__ inline u16 f2b(float f) {
    __hip_bfloat16 h = __float2bfloat16(f);
    return *reinterpret_cast<u16*>(&h);
}
__device__ inline void storeval(float* p, float v) { *p = v; }
__device__ inline void storeval(u16* p, float v) { *p = f2b(v); }

// async global->LDS, 16B per lane. LDS dest must be linear in lane within wave.
__device__ inline void gload16(const u16* g, u16* l) {
    __builtin_amdgcn_global_load_lds(
        (__attribute__((address_space(1))) void*)(g),
        (__attribute__((address_space(3))) void*)(l), 16, 0, 0);
}

// ---------------------------------------------------------------- span max
__global__ __launch_bounds__(256) void span_kernel(const float* __restrict__ enc,
                                                   float* __restrict__ X,
                                                   u16* __restrict__ Xb) {
    int i = blockIdx.x, b = blockIdx.y, h = threadIdx.x;
    int tb = i * SEQ - (i * (i - 1)) / 2 - i;   // t = tb + j
    float run = -1e30f;
    for (int j = i; j < SEQ; ++j) {
        run = fmaxf(run, enc[((size_t)b * SEQ + j) * DMODEL + h]);
        size_t idx = ((size_t)b * NV + tb + j) * DMODEL + h;
        X[idx] = run;
        Xb[idx] = f2b(run);
    }
}

// ---------------------------------------------------------------- all weight casts, one launch
// float4-group counts: iw 98304 | ow 32768 | f1w 262144 | f2w 262144 (total 655360)
__global__ __launch_bounds__(256) void castall_kernel(
    const float* __restrict__ iw, const float* __restrict__ ow,
    const float* __restrict__ f1w, const float* __restrict__ f2w,
    u16* __restrict__ iwb, u16* __restrict__ owb,
    u16* __restrict__ f1wb, u16* __restrict__ f2wb) {
    int i = blockIdx.x * 256 + threadIdx.x;
    const float* src;
    u16* dst;
    int off;
    if (i < 98304)       { src = iw;  dst = iwb;  off = i; }
    else if (i < 131072) { src = ow;  dst = owb;  off = i - 98304; }
    else if (i < 393216) { src = f1w; dst = f1wb; off = i - 131072; }
    else                 { src = f2w; dst = f2wb; off = i - 393216; }
    float4 v = *(const float4*)(src + (size_t)off * 4);
    *(ushort4*)(dst + (size_t)off * 4) =
        make_ushort4(f2b(v.x), f2b(v.y), f2b(v.z), f2b(v.w));
}

// ---------------------------------------------------------------- MFMA GEMM 64x64 (legacy, for narrow GEMMs)
template <typename OutT, bool RELU, bool ATOMIC>
__global__ __launch_bounds__(256) void mm_kernel(
    const u16* __restrict__ A, const u16* __restrict__ W,
    const float* __restrict__ bias, const float* __restrict__ Res,
    OutT* __restrict__ C, int N, int K, int lda, int ldw, int ldc,
    float alpha, int WV, int KC) {
    __shared__ u16 As[64][40];
    __shared__ u16 Ws[64][40];
    const float4 fz = make_float4(0.f, 0.f, 0.f, 0.f);
    int ks = blockIdx.z;
    int kb = ks * KC, ke = min(K, kb + KC);
    int p0 = blockIdx.x * 64, n0 = blockIdx.y * 64;
    int tid = threadIdx.x, lane = tid & 63, w = tid >> 6;
    int col_l = lane & 15, quad = lane >> 4;
    f32x4 acc[4] = {};
    for (int k0 = kb; k0 < ke; k0 += 32) {
        int r = tid >> 2, seg = (tid & 3) * 8;
        {
            int gn = n0 + r;
            float4 av = fz;
            if (gn < N) av = *(const float4*)(A + (size_t)gn * lda + k0 + seg);
            *(float4*)&As[r][seg] = av;
        }
        {
            int gp = p0 + r;
            float4 wv = fz;
            if (gp < WV) wv = *(const float4*)(W + (size_t)gp * ldw + k0 + seg);
            *(float4*)&Ws[r][seg] = wv;
        }
        __syncthreads();
        bf16x8 a = *(const bf16x8*)&As[w * 16 + col_l][quad * 8];
#pragma unroll
        for (int c = 0; c < 4; ++c) {
            bf16x8 b = *(const bf16x8*)&Ws[c * 16 + col_l][quad * 8];
            acc[c] = __builtin_amdgcn_mfma_f32_16x16x32_bf16(a, b, acc[c], 0, 0, 0);
        }
        __syncthreads();
    }
#pragma unroll
    for (int c = 0; c < 4; ++c) {
        int col = p0 + c * 16 + col_l;
        float bv = bias ? bias[col] : 0.f;
#pragma unroll
        for (int reg = 0; reg < 4; ++reg) {
            int row = n0 + w * 16 + quad * 4 + reg;
            if (row < N) {
                float v = acc[c][reg] * alpha + bv;
                if (Res) v += Res[(size_t)row * ldc + col];
                if (RELU) v = fmaxf(v, 0.f);
                if (ATOMIC) {
                    unsafeAtomicAdd((float*)&C[(size_t)row * ldc + col], v);
                } else {
                    storeval(&C[(size_t)row * ldc + col], v);
                }
            }
        }
    }
}

// ---------------------------------------------------------------- MFMA GEMM 128x128 (m97 structure)
// 4 waves (2x2), BK=32, global_load_lds width-16 staging, linear LDS.
// Requires: row dim of A buffer padded to >= gridDim.y*128; col dim (WV) multiple of 128.
template <typename OutT, bool RELU, bool ATOMIC>
__global__ __launch_bounds__(256) void mm128_kernel(
    const u16* __restrict__ A, const u16* __restrict__ W,
    const float* __restrict__ bias,
    OutT* __restrict__ C, int N, int lda, int ldw, int ldc, int KC) {
    __shared__ u16 As[128][32];
    __shared__ u16 Ws[128][32];
    int k0b = blockIdx.z * KC;
    int p0 = blockIdx.x * 128, n0 = blockIdx.y * 128;
    int tid = threadIdx.x, lane = tid & 63, w = tid >> 6;
    int col_l = lane & 15, quad = lane >> 4;
    int wr = w >> 1, wc = w & 1;
    // staging: each thread 16B; tile row = tid/4 (+64 for round 1), col = (tid&3)*8 elems
    int ra = tid >> 2, ca = (tid & 3) * 8;
    const u16* Abase = A + (size_t)(n0 + ra) * lda + ca;
    const u16* Wbase = W + (size_t)(p0 + ra) * ldw + ca;
    f32x4 acc[4][4] = {};
    for (int kk = 0; kk < KC; kk += 32) {
        int k0 = k0b + kk;
        gload16(Abase + k0, &As[ra][ca]);
        gload16(Abase + (size_t)64 * lda + k0, &As[64 + ra][ca]);
        gload16(Wbase + k0, &Ws[ra][ca]);
        gload16(Wbase + (size_t)64 * ldw + k0, &Ws[64 + ra][ca]);
        __syncthreads();
        bf16x8 a[4], b[4];
#pragma unroll
        for (int m = 0; m < 4; ++m)
            a[m] = *(const bf16x8*)&As[wr * 64 + m * 16 + col_l][quad * 8];
#pragma unroll
        for (int c = 0; c < 4; ++c)
            b[c] = *(const bf16x8*)&Ws[wc * 64 + c * 16 + col_l][quad * 8];
#pragma unroll
        for (int m = 0; m < 4; ++m)
#pragma unroll
            for (int c = 0; c < 4; ++c)
                acc[m][c] = __builtin_amdgcn_mfma_f32_16x16x32_bf16(a[m], b[c],
                                                                    acc[m][c], 0, 0, 0);
        __syncthreads();
    }
#pragma unroll
    for (int c = 0; c < 4; ++c) {
        int col = p0 + wc * 64 + c * 16 + col_l;
        float bv = bias ? bias[col] : 0.f;
#pragma unroll
        for (int m = 0; m < 4; ++m) {
#pragma unroll
            for (int reg = 0; reg < 4; ++reg) {
                int row = n0 + wr * 64 + m * 16 + quad * 4 + reg;
                if (row < N) {
                    float v = acc[m][c][reg] + bv;
                    if (RELU) v = fmaxf(v, 0.f);
                    if (ATOMIC) {
                        unsafeAtomicAdd((float*)&C[(size_t)row * ldc + col], v);
                    } else {
                        storeval(&C[(size_t)row * ldc + col], v);
                    }
                }
            }
        }
    }
}

// ---------------------------------------------------------------- V transpose
// VT[bh][d][key] = V[b,key,h,d]; keys >= NV zeroed.
__global__ __launch_bounds__(256) void vtrans_kernel(const u16* __restrict__ QKVb,
                                                     u16* __restrict__ VT) {
    __shared__ u16 T[64][66];
    const float4 fz = make_float4(0.f, 0.f, 0.f, 0.f);
    int kt = blockIdx.x, dt = blockIdx.y, bh = blockIdx.z;
    int b = bh >> 1, h = bh & 1;
    size_t rb = (size_t)b * NV;
    int tid = threadIdx.x;
    {
        int r = tid >> 2, cs = (tid & 3) * 16;
        int key = kt * 64 + r;
        float4 v0 = fz, v1 = fz;
        if (key < NV) {
            const u16* vp = QKVb + (rb + key) * 768 + 2 * DMODEL + h * HD + dt * 64 + cs;
            v0 = *(const float4*)vp;
            v1 = *(const float4*)(vp + 8);
        }
        *(float4*)&T[r][cs] = v0;
        *(float4*)&T[r][cs + 8] = v1;
    }
    __syncthreads();
    {
        int dl = tid >> 2, ks2 = (tid & 3) * 16;
        u16 tmp[16];
#pragma unroll
        for (int j = 0; j < 16; ++j) tmp[j] = T[ks2 + j][dl];
        u16* dst = VT + ((size_t)bh * HD + dt * 64 + dl) * NVP + kt * 64 + ks2;
        *(float4*)dst = *(float4*)&tmp[0];
        *(float4*)(dst + 8) = *(float4*)&tmp[8];
    }
}

// ---------------------------------------------------------------- flash-decoding attention
// grid (19 qtiles, 8 bh, KSPLIT). Each block: 64 queries x one key chunk
// (4 key-tiles of 64; last split has 3). Writes unnormalized partials.
__global__ __launch_bounds__(256) void flash_kernel(const u16* __restrict__ QKVb,
                                                    const u16* __restrict__ VT,
                                                    float* __restrict__ Opart,
                                                    float* __restrict__ ML) {
    __shared__ u16 Ks[64][136];
    __shared__ u16 Vt[128][72];
    __shared__ u16 Ps[4][16][72];
    const float4 fz = make_float4(0.f, 0.f, 0.f, 0.f);
    int tid = threadIdx.x, lane = tid & 63, w = tid >> 6;
    int col_l = lane & 15, quad = lane >> 4;
    int bh = blockIdx.y, b = bh >> 1, h = bh & 1;
    int ks = blockIdx.z;
    int t0 = ks * 4, tcnt = min(4, 19 - t0);
    size_t rb = (size_t)b * NV;
    int q0 = blockIdx.x * 64, wq0 = q0 + w * 16;

    // Q fragments in registers: A[m=col_l][k=quad*8+j], 4 k-frags (K=128)
    float4 qv[4];
    {
        int qrow = wq0 + col_l;
        if (qrow < NV) {
            const u16* qp = QKVb + (rb + qrow) * 768 + h * HD + quad * 8;
#pragma unroll
            for (int kf = 0; kf < 4; ++kf) qv[kf] = *(const float4*)(qp + kf * 32);
        } else {
#pragma unroll
            for (int kf = 0; kf < 4; ++kf) qv[kf] = fz;
        }
    }

    f32x4 oacc[8] = {};
    float m_run[4], l_run[4];
#pragma unroll
    for (int r = 0; r < 4; ++r) { m_run[r] = -1e30f; l_run[r] = 0.f; }

    for (int it = 0; it < tcnt; ++it) {
        int kt = (t0 + it) * 64;
        {   // stage K tile: 64 keys x 128 d (vectorized)
            int r = tid >> 2, seg = (tid & 3) * 32;
            int key = kt + r;
            const u16* kp = QKVb + (rb + key) * 768 + DMODEL + h * HD + seg;
#pragma unroll
            for (int t4 = 0; t4 < 4; ++t4) {
                float4 v = fz;
                if (key < NV) v = *(const float4*)(kp + t4 * 8);
                *(float4*)&Ks[r][seg + t4 * 8] = v;
            }
        }
        {   // stage V^T tile from VT: 128 d x 64 keys (vectorized)
            int d = tid >> 1, half = (tid & 1) * 32;
            const u16* vp = VT + ((size_t)bh * HD + d) * NVP + kt + half;
#pragma unroll
            for (int t4 = 0; t4 < 4; ++t4)
                *(float4*)&Vt[d][half + t4 * 8] = *(const float4*)(vp + t4 * 8);
        }
        __syncthreads();

        // S = Q K^T : 16 q-rows x 64 keys per wave
        f32x4 s[4] = {};
#pragma unroll
        for (int c = 0; c < 4; ++c)
#pragma unroll
            for (int kf = 0; kf < 4; ++kf) {
                bf16x8 kfr = *(const bf16x8*)&Ks[c * 16 + col_l][kf * 32 + quad * 8];
                s[c] = __builtin_amdgcn_mfma_f32_16x16x32_bf16(
                    *(const bf16x8*)&qv[kf], kfr, s[c], 0, 0, 0);
            }

        float pv[4][4];
#pragma unroll
        for (int c = 0; c < 4; ++c) {
            bool kvalid = (kt + c * 16 + col_l) < NV;
#pragma unroll
            for (int r = 0; r < 4; ++r)
                pv[c][r] = kvalid ? s[c][r] * SCALE : -1e30f;
        }
        float al[4];
#pragma unroll
        for (int r = 0; r < 4; ++r) {
            float mx = fmaxf(fmaxf(pv[0][r], pv[1][r]), fmaxf(pv[2][r], pv[3][r]));
#pragma unroll
            for (int off = 1; off < 16; off <<= 1)
                mx = fmaxf(mx, __shfl_xor(mx, off));
            float mn = fmaxf(m_run[r], mx);
            al[r] = __expf(m_run[r] - mn);
            m_run[r] = mn;
            float sum = 0.f;
#pragma unroll
            for (int c = 0; c < 4; ++c) {
                float p = __expf(pv[c][r] - mn);
                pv[c][r] = p;
                sum += p;
            }
#pragma unroll
            for (int off = 1; off < 16; off <<= 1) sum += __shfl_xor(sum, off);
            l_run[r] = l_run[r] * al[r] + sum;
        }
#pragma unroll
        for (int ct = 0; ct < 8; ++ct)
#pragma unroll
            for (int r = 0; r < 4; ++r) oacc[ct][r] *= al[r];

        // P C-layout -> per-wave LDS -> A-layout (DS in-order per wave, no barrier)
#pragma unroll
        for (int c = 0; c < 4; ++c)
#pragma unroll
            for (int r = 0; r < 4; ++r)
                Ps[w][quad * 4 + r][c * 16 + col_l] = f2b(pv[c][r]);
        bf16x8 pf0 = *(const bf16x8*)&Ps[w][col_l][quad * 8];
        bf16x8 pf1 = *(const bf16x8*)&Ps[w][col_l][32 + quad * 8];
#pragma unroll
        for (int ct = 0; ct < 8; ++ct) {
            bf16x8 v0 = *(const bf16x8*)&Vt[ct * 16 + col_l][quad * 8];
            bf16x8 v1 = *(const bf16x8*)&Vt[ct * 16 + col_l][32 + quad * 8];
            oacc[ct] = __builtin_amdgcn_mfma_f32_16x16x32_bf16(pf0, v0, oacc[ct], 0, 0, 0);
            oacc[ct] = __builtin_amdgcn_mfma_f32_16x16x32_bf16(pf1, v1, oacc[ct], 0, 0, 0);
        }
        __syncthreads();
    }

    // store unnormalized partials
    size_t slab = (size_t)(ks * 8 + bh) * NVP;
#pragma unroll
    for (int ct = 0; ct < 8; ++ct)
#pragma unroll
        for (int r = 0; r < 4; ++r) {
            int row = wq0 + quad * 4 + r;
            Opart[(slab + row) * HD + ct * 16 + col_l] = oacc[ct][r];
        }
    if (col_l == 0) {
#pragma unroll
        for (int r = 0; r < 4; ++r) {
            int row = wq0 + quad * 4 + r;
            ML[(slab + row) * 2 + 0] = m_run[r];
            ML[(slab + row) * 2 + 1] = l_run[r];
        }
    }
}

// ---------------------------------------------------------------- combine splits
// grid (588, 8): block = 2 rows x 128 d.
__global__ __launch_bounds__(256) void comb_kernel(const float* __restrict__ Opart,
                                                   const float* __restrict__ ML,
                                                   u16* __restrict__ Obuf) {
    int bh = blockIdx.y, b = bh >> 1, h = bh & 1;
    int tid = threadIdx.x;
    int row = blockIdx.x * 2 + (tid >> 7);
    int d = tid & 127;
    if (row >= NV) return;
    float m[KSPLIT], l[KSPLIT];
#pragma unroll
    for (int i = 0; i < KSPLIT; ++i) {
        size_t mb = ((size_t)(i * 8 + bh) * NVP + row) * 2;
        m[i] = ML[mb];
        l[i] = ML[mb + 1];
    }
    float M = m[0];
#pragma unroll
    for (int i = 1; i < KSPLIT; ++i) M = fmaxf(M, m[i]);
    float wsum = 0.f, o = 0.f;
#pragma unroll
    for (int i = 0; i < KSPLIT; ++i) {
        float wi = __expf(m[i] - M);
        wsum += l[i] * wi;
        o += Opart[((size_t)(i * 8 + bh) * NVP + row) * HD + d] * wi;
    }
    Obuf[((size_t)b * NV + row) * DMODEL + h * HD + d] = f2b(o / wsum);
}

// ---------------------------------------------------------------- residual + LN (+opt FFN2 prefill)
__global__ __launch_bounds__(256) void ln_kernel(const float* __restrict__ Xin,
                                                 const float* __restrict__ Res,
                                                 const float* __restrict__ w,
                                                 const float* __restrict__ bb,
                                                 float* __restrict__ Y,
                                                 u16* __restrict__ Yb,
                                                 const float* __restrict__ fb2,
                                                 float* __restrict__ A2out) {
    int r = blockIdx.x, d = threadIdx.x;
    size_t idx = (size_t)r * DMODEL + d;
    float v = Xin[idx];
    if (Res) v += Res[idx];
    float s1 = v, s2 = v * v;
#pragma unroll
    for (int off = 32; off > 0; off >>= 1) {
        s1 += __shfl_down(s1, off);
        s2 += __shfl_down(s2, off);
    }
    __shared__ float ps1[4], ps2[4];
    int wid = d >> 6, lane = d & 63;
    if (lane == 0) { ps1[wid] = s1; ps2[wid] = s2; }
    __syncthreads();
    if (d == 0) {
        ps1[0] = ps1[0] + ps1[1] + ps1[2] + ps1[3];
        ps2[0] = ps2[0] + ps2[1] + ps2[2] + ps2[3];
    }
    __syncthreads();
    float mean = ps1[0] * (1.f / DMODEL);
    float var = ps2[0] * (1.f / DMODEL) - mean * mean;
    float o = (v - mean) * rsqrtf(var + 1e-5f) * w[d] + bb[d];
    Y[idx] = o;
    Yb[idx] = f2b(o);
    if (A2out) A2out[idx] = o + fb2[d];   // FFN2 split-K prefill: X + bias
}

// ---------------------------------------------------------------- gather
__global__ __launch_bounds__(256) void gather_kernel(const float* __restrict__ Xf,
                                                     const int* __restrict__ s1,
                                                     const int* __restrict__ e1,
                                                     const int* __restrict__ qb,
                                                     const int* __restrict__ s2,
                                                     const int* __restrict__ e2,
                                                     float* __restrict__ out) {
    int q = blockIdx.x, which = blockIdx.y, d = threadIdx.x;
    int s = which ? s2[q] : s1[q];
    int e = which ? e2[q] : e1[q];
    int b = qb[q];
    int t = s * SEQ - (s * (s - 1)) / 2 + (e - s);
    if (t < 0) t = 0;
    if (t >= NV) t = NV - 1;
    out[((size_t)which * NQ_C + q) * DMODEL + d] = Xf[((size_t)b * NV + t) * DMODEL + d];
}

// ---------------------------------------------------------------- launch
extern "C" void kernel_launch(void* const* d_in, const int* in_sizes, int n_in,
                              void* d_out, int out_size, void* d_ws, size_t ws_size,
                              hipStream_t stream) {
    const float* enc = (const float*)d_in[0];
    const float* iw  = (const float*)d_in[1];
    const float* ib  = (const float*)d_in[2];
    const float* ow  = (const float*)d_in[3];
    const float* ob  = (const float*)d_in[4];
    const float* l1w = (const float*)d_in[5];
    const float* l1b = (const float*)d_in[6];
    const float* l2w = (const float*)d_in[7];
    const float* l2b = (const float*)d_in[8];
    const float* f1w = (const float*)d_in[9];
    const float* f1b = (const float*)d_in[10];
    const float* f2w = (const float*)d_in[11];
    const float* f2b_ = (const float*)d_in[12];
    const float* flw = (const float*)d_in[13];
    const float* flb = (const float*)d_in[14];
    const int* s1 = (const int*)d_in[15];
    const int* e1 = (const int*)d_in[16];
    const int* qb = (const int*)d_in[17];
    const int* s2 = (const int*)d_in[18];
    const int* e2 = (const int*)d_in[19];
    float* out = (float*)d_out;

    // ---------------- workspace layout (~55 MB) ----------------
    char* p = (char*)d_ws;
    float* X     = (float*)p;  p += (size_t)NTOT * DMODEL * 4;
    float* A2    = (float*)p;  p += (size_t)NTOT * DMODEL * 4;
    u16* Xb      = (u16*)p;    p += (size_t)NTOTP * DMODEL * 2;   // padded rows for mm128
    u16* Obuf    = (u16*)p;    p += (size_t)NTOT * DMODEL * 2;
    u16* QKVb    = (u16*)p;    p += (size_t)NTOT * 3 * DMODEL * 2;
    u16* VT      = (u16*)p;    p += (size_t)8 * HD * NVP * 2;
    float* ML    = (float*)p;  p += (size_t)KSPLIT * 8 * NVP * 2 * 4;
    float* Opart = (float*)p;  p += (size_t)KSPLIT * 8 * NVP * HD * 4;
    u16* wb      = (u16*)p;
    u16* F1b     = (u16*)Opart;  // alias: FFN phase doesn't overlap attention phase
                                 // (NTOTP*DFF*2 = 19.4 MB <= Opart 24.9 MB)
    float* Of    = A2;           // alias: final LN output

    u16* iwb  = wb;
    u16* owb  = iwb + 2 * 3 * DMODEL * DMODEL;
    u16* f1wb = owb + 2 * DMODEL * DMODEL;
    u16* f2wb = f1wb + 2 * DFF_C * DMODEL;

    castall_kernel<<<dim3(2560), 256, 0, stream>>>(iw, ow, f1w, f2w,
                                                   iwb, owb, f1wb, f2wb);
    span_kernel<<<dim3(SEQ, BSZ), 256, 0, stream>>>(enc, X, Xb);

    for (int l = 0; l < NLAYERS; ++l) {
        // QKV = Xb @ iw^T + ib -> bf16 [NTOT][768]   (128x128 gload_lds GEMM)
        mm128_kernel<u16, false, false><<<dim3(6, 37, 1), 256, 0, stream>>>(
            Xb, iwb + (size_t)l * 3 * DMODEL * DMODEL, ib + (size_t)l * 3 * DMODEL,
            QKVb, NTOT, DMODEL, DMODEL, 3 * DMODEL, DMODEL);
        // V^T per (b,h)
        vtrans_kernel<<<dim3(19, 2, 8), 256, 0, stream>>>(QKVb, VT);
        // flash-decoding attention partials + combine
        flash_kernel<<<dim3(19, 8, KSPLIT), 256, 0, stream>>>(QKVb, VT, Opart, ML);
        comb_kernel<<<dim3(588, 8), 256, 0, stream>>>(Opart, ML, Obuf);
        // A2 = X + Obuf @ ow^T + ob -> fp32 (residual fused; narrow N -> keep 64x64)
        mm_kernel<float, false, false><<<dim3(4, 74, 1), 256, 0, stream>>>(
            Obuf, owb + (size_t)l * DMODEL * DMODEL, ob + (size_t)l * DMODEL,
            X, A2, NTOT, DMODEL, DMODEL, DMODEL, DMODEL, 1.f, DMODEL, DMODEL);
        // LN1 (+ prefill A2 = X + f2b for split-K FFN2)
        ln_kernel<<<dim3(NTOT), 256, 0, stream>>>(
            A2, nullptr, l1w + (size_t)l * DMODEL, l1b + (size_t)l * DMODEL,
            X, Xb, f2b_ + (size_t)l * DMODEL, A2);
        // F1 = relu(Xb @ f1w^T + f1b) -> bf16   (128x128 gload_lds GEMM)
        mm128_kernel<u16, true, false><<<dim3(16, 37, 1), 256, 0, stream>>>(
            Xb, f1wb + (size_t)l * DFF_C * DMODEL, f1b + (size_t)l * DFF_C,
            F1b, NTOT, DMODEL, DMODEL, DFF_C, DMODEL);
        // A2 += F1 @ f2w^T (split-K x4, atomic)   (128x128 gload_lds GEMM)
        mm128_kernel<float, false, true><<<dim3(2, 37, 4), 256, 0, stream>>>(
            F1b, f2wb + (size_t)l * DMODEL * DFF_C, nullptr, A2,
            NTOT, DFF_C, DFF_C, DMODEL, 512);
        ln_kernel<<<dim3(NTOT), 256, 0, stream>>>(
            A2, nullptr, l2w + (size_t)l * DMODEL, l2b + (size_t)l * DMODEL,
            X, Xb, nullptr, nullptr);
    }
    ln_kernel<<<dim3(NTOT), 256, 0, stream>>>(X, nullptr, flw, flb, Of, Xb,
                                              nullptr, nullptr);
    gather_kernel<<<dim3(NQ_C, 2), 256, 0, stream>>>(Of, s1, e1, qb, s2, e2, out);
}

// Round 4
// 346.727 us; speedup vs baseline: 1.0866x; 1.0866x over previous
//
#include <hip/hip_runtime.h>
#include <hip/hip_bf16.h>

#define BSZ 4
#define SEQ 48
#define DMODEL 256
#define NHEAD 2
#define HD 128
#define NLAYERS 2
#define DFF_C 2048
#define NQ_C 512
#define NV 1176                 /* valid spans per batch: 48*49/2 */
#define NTOT (BSZ * NV)         /* 4704 */
#define NVP 1216                /* NV padded to 64 multiple (19*64) */
#define KSPLIT 5                /* key splits for flash-decoding */
#define SCALE 0.088388347648318447f   /* 1/sqrt(128) */

typedef unsigned short u16;
typedef __attribute__((ext_vector_type(8))) short bf16x8;
typedef __attribute__((ext_vector_type(4))) float f32x4;

__device__ inline u16 f2b(float f) {
    __hip_bfloat16 h = __float2bfloat16(f);
    return *reinterpret_cast<u16*>(&h);
}
__device__ inline void storeval(float* p, float v) { *p = v; }
__device__ inline void storeval(u16* p, float v) { *p = f2b(v); }

// ---------------------------------------------------------------- span max
__global__ __launch_bounds__(256) void span_kernel(const float* __restrict__ enc,
                                                   float* __restrict__ X,
                                                   u16* __restrict__ Xb) {
    int i = blockIdx.x, b = blockIdx.y, h = threadIdx.x;
    int tb = i * SEQ - (i * (i - 1)) / 2 - i;   // t = tb + j
    float run = -1e30f;
    for (int j = i; j < SEQ; ++j) {
        run = fmaxf(run, enc[((size_t)b * SEQ + j) * DMODEL + h]);
        size_t idx = ((size_t)b * NV + tb + j) * DMODEL + h;
        X[idx] = run;
        Xb[idx] = f2b(run);
    }
}

// ---------------------------------------------------------------- all weight casts, one launch
// float4-group counts: iw 98304 | ow 32768 | f1w 262144 | f2w 262144 (total 655360)
__global__ __launch_bounds__(256) void castall_kernel(
    const float* __restrict__ iw, const float* __restrict__ ow,
    const float* __restrict__ f1w, const float* __restrict__ f2w,
    u16* __restrict__ iwb, u16* __restrict__ owb,
    u16* __restrict__ f1wb, u16* __restrict__ f2wb) {
    int i = blockIdx.x * 256 + threadIdx.x;
    const float* src;
    u16* dst;
    int off;
    if (i < 98304)       { src = iw;  dst = iwb;  off = i; }
    else if (i < 131072) { src = ow;  dst = owb;  off = i - 98304; }
    else if (i < 393216) { src = f1w; dst = f1wb; off = i - 131072; }
    else                 { src = f2w; dst = f2wb; off = i - 393216; }
    float4 v = *(const float4*)(src + (size_t)off * 4);
    *(ushort4*)(dst + (size_t)off * 4) =
        make_ushort4(f2b(v.x), f2b(v.y), f2b(v.z), f2b(v.w));
}

// ---------------------------------------------------------------- MFMA GEMM 64x64, BK=64
// C[n,p] = alpha*sum_{k in split}A[n,k]*W[p,k] + bias[p] (+Res) (+relu).
// ATOMIC: atomically accumulate into fp32 C (bias/Res pre-applied elsewhere).
// BK=64: half the barriers of BK=32; per-element k-chunk accumulation order
// (kb, kb+32, kb+64, ...) identical to BK=32 -> bit-exact vs baseline.
template <typename OutT, bool RELU, bool ATOMIC>
__global__ __launch_bounds__(256) void mm_kernel(
    const u16* __restrict__ A, const u16* __restrict__ W,
    const float* __restrict__ bias, const float* __restrict__ Res,
    OutT* __restrict__ C, int N, int K, int lda, int ldw, int ldc,
    float alpha, int WV, int KC) {
    __shared__ u16 As[64][72];
    __shared__ u16 Ws[64][72];
    const float4 fz = make_float4(0.f, 0.f, 0.f, 0.f);
    int ks = blockIdx.z;
    int kb = ks * KC, ke = min(K, kb + KC);
    int p0 = blockIdx.x * 64, n0 = blockIdx.y * 64;
    int tid = threadIdx.x, lane = tid & 63, w = tid >> 6;
    int col_l = lane & 15, quad = lane >> 4;
    f32x4 acc[4] = {};
    for (int k0 = kb; k0 < ke; k0 += 64) {
        int r = tid >> 2, seg = (tid & 3) * 16;
        {
            int gn = n0 + r;
            float4 a0 = fz, a1 = fz;
            if (gn < N) {
                const u16* ap = A + (size_t)gn * lda + k0 + seg;
                a0 = *(const float4*)ap;
                a1 = *(const float4*)(ap + 8);
            }
            *(float4*)&As[r][seg] = a0;
            *(float4*)&As[r][seg + 8] = a1;
        }
        {
            int gp = p0 + r;
            float4 w0 = fz, w1 = fz;
            if (gp < WV) {
                const u16* wp = W + (size_t)gp * ldw + k0 + seg;
                w0 = *(const float4*)wp;
                w1 = *(const float4*)(wp + 8);
            }
            *(float4*)&Ws[r][seg] = w0;
            *(float4*)&Ws[r][seg + 8] = w1;
        }
        __syncthreads();
        bf16x8 a0 = *(const bf16x8*)&As[w * 16 + col_l][quad * 8];
        bf16x8 a1 = *(const bf16x8*)&As[w * 16 + col_l][32 + quad * 8];
#pragma unroll
        for (int c = 0; c < 4; ++c) {
            bf16x8 b0 = *(const bf16x8*)&Ws[c * 16 + col_l][quad * 8];
            bf16x8 b1 = *(const bf16x8*)&Ws[c * 16 + col_l][32 + quad * 8];
            acc[c] = __builtin_amdgcn_mfma_f32_16x16x32_bf16(a0, b0, acc[c], 0, 0, 0);
            acc[c] = __builtin_amdgcn_mfma_f32_16x16x32_bf16(a1, b1, acc[c], 0, 0, 0);
        }
        __syncthreads();
    }
#pragma unroll
    for (int c = 0; c < 4; ++c) {
        int col = p0 + c * 16 + col_l;
        float bv = bias ? bias[col] : 0.f;
#pragma unroll
        for (int reg = 0; reg < 4; ++reg) {
            int row = n0 + w * 16 + quad * 4 + reg;
            if (row < N) {
                float v = acc[c][reg] * alpha + bv;
                if (Res) v += Res[(size_t)row * ldc + col];
                if (RELU) v = fmaxf(v, 0.f);
                if (ATOMIC) {
                    unsafeAtomicAdd((float*)&C[(size_t)row * ldc + col], v);
                } else {
                    storeval(&C[(size_t)row * ldc + col], v);
                }
            }
        }
    }
}

// ---------------------------------------------------------------- V transpose
// VT[bh][d][key] = V[b,key,h,d]; keys >= NV zeroed.
__global__ __launch_bounds__(256) void vtrans_kernel(const u16* __restrict__ QKVb,
                                                     u16* __restrict__ VT) {
    __shared__ u16 T[64][66];
    const float4 fz = make_float4(0.f, 0.f, 0.f, 0.f);
    int kt = blockIdx.x, dt = blockIdx.y, bh = blockIdx.z;
    int b = bh >> 1, h = bh & 1;
    size_t rb = (size_t)b * NV;
    int tid = threadIdx.x;
    {
        int r = tid >> 2, cs = (tid & 3) * 16;
        int key = kt * 64 + r;
        float4 v0 = fz, v1 = fz;
        if (key < NV) {
            const u16* vp = QKVb + (rb + key) * 768 + 2 * DMODEL + h * HD + dt * 64 + cs;
            v0 = *(const float4*)vp;
            v1 = *(const float4*)(vp + 8);
        }
        *(float4*)&T[r][cs] = v0;
        *(float4*)&T[r][cs + 8] = v1;
    }
    __syncthreads();
    {
        int dl = tid >> 2, ks2 = (tid & 3) * 16;
        u16 tmp[16];
#pragma unroll
        for (int j = 0; j < 16; ++j) tmp[j] = T[ks2 + j][dl];
        u16* dst = VT + ((size_t)bh * HD + dt * 64 + dl) * NVP + kt * 64 + ks2;
        *(float4*)dst = *(float4*)&tmp[0];
        *(float4*)(dst + 8) = *(float4*)&tmp[8];
    }
}

// ---------------------------------------------------------------- flash-decoding attention
// grid (19 qtiles, 8 bh, KSPLIT). Each block: 64 queries x one key chunk
// (4 key-tiles of 64; last split has 3). Writes unnormalized partials.
__global__ __launch_bounds__(256) void flash_kernel(const u16* __restrict__ QKVb,
                                                    const u16* __restrict__ VT,
                                                    float* __restrict__ Opart,
                                                    float* __restrict__ ML) {
    __shared__ u16 Ks[64][136];
    __shared__ u16 Vt[128][72];
    __shared__ u16 Ps[4][16][72];
    const float4 fz = make_float4(0.f, 0.f, 0.f, 0.f);
    int tid = threadIdx.x, lane = tid & 63, w = tid >> 6;
    int col_l = lane & 15, quad = lane >> 4;
    int bh = blockIdx.y, b = bh >> 1, h = bh & 1;
    int ks = blockIdx.z;
    int t0 = ks * 4, tcnt = min(4, 19 - t0);
    size_t rb = (size_t)b * NV;
    int q0 = blockIdx.x * 64, wq0 = q0 + w * 16;

    // Q fragments in registers: A[m=col_l][k=quad*8+j], 4 k-frags (K=128)
    float4 qv[4];
    {
        int qrow = wq0 + col_l;
        if (qrow < NV) {
            const u16* qp = QKVb + (rb + qrow) * 768 + h * HD + quad * 8;
#pragma unroll
            for (int kf = 0; kf < 4; ++kf) qv[kf] = *(const float4*)(qp + kf * 32);
        } else {
#pragma unroll
            for (int kf = 0; kf < 4; ++kf) qv[kf] = fz;
        }
    }

    f32x4 oacc[8] = {};
    float m_run[4], l_run[4];
#pragma unroll
    for (int r = 0; r < 4; ++r) { m_run[r] = -1e30f; l_run[r] = 0.f; }

    for (int it = 0; it < tcnt; ++it) {
        int kt = (t0 + it) * 64;
        {   // stage K tile: 64 keys x 128 d (vectorized)
            int r = tid >> 2, seg = (tid & 3) * 32;
            int key = kt + r;
            const u16* kp = QKVb + (rb + key) * 768 + DMODEL + h * HD + seg;
#pragma unroll
            for (int t4 = 0; t4 < 4; ++t4) {
                float4 v = fz;
                if (key < NV) v = *(const float4*)(kp + t4 * 8);
                *(float4*)&Ks[r][seg + t4 * 8] = v;
            }
        }
        {   // stage V^T tile from VT: 128 d x 64 keys (vectorized)
            int d = tid >> 1, half = (tid & 1) * 32;
            const u16* vp = VT + ((size_t)bh * HD + d) * NVP + kt + half;
#pragma unroll
            for (int t4 = 0; t4 < 4; ++t4)
                *(float4*)&Vt[d][half + t4 * 8] = *(const float4*)(vp + t4 * 8);
        }
        __syncthreads();

        // S = Q K^T : 16 q-rows x 64 keys per wave
        f32x4 s[4] = {};
#pragma unroll
        for (int c = 0; c < 4; ++c)
#pragma unroll
            for (int kf = 0; kf < 4; ++kf) {
                bf16x8 kfr = *(const bf16x8*)&Ks[c * 16 + col_l][kf * 32 + quad * 8];
                s[c] = __builtin_amdgcn_mfma_f32_16x16x32_bf16(
                    *(const bf16x8*)&qv[kf], kfr, s[c], 0, 0, 0);
            }

        float pv[4][4];
#pragma unroll
        for (int c = 0; c < 4; ++c) {
            bool kvalid = (kt + c * 16 + col_l) < NV;
#pragma unroll
            for (int r = 0; r < 4; ++r)
                pv[c][r] = kvalid ? s[c][r] * SCALE : -1e30f;
        }
        float al[4];
#pragma unroll
        for (int r = 0; r < 4; ++r) {
            float mx = fmaxf(fmaxf(pv[0][r], pv[1][r]), fmaxf(pv[2][r], pv[3][r]));
#pragma unroll
            for (int off = 1; off < 16; off <<= 1)
                mx = fmaxf(mx, __shfl_xor(mx, off));
            float mn = fmaxf(m_run[r], mx);
            al[r] = __expf(m_run[r] - mn);
            m_run[r] = mn;
            float sum = 0.f;
#pragma unroll
            for (int c = 0; c < 4; ++c) {
                float p = __expf(pv[c][r] - mn);
                pv[c][r] = p;
                sum += p;
            }
#pragma unroll
            for (int off = 1; off < 16; off <<= 1) sum += __shfl_xor(sum, off);
            l_run[r] = l_run[r] * al[r] + sum;
        }
#pragma unroll
        for (int ct = 0; ct < 8; ++ct)
#pragma unroll
            for (int r = 0; r < 4; ++r) oacc[ct][r] *= al[r];

        // P C-layout -> per-wave LDS -> A-layout (DS in-order per wave, no barrier)
#pragma unroll
        for (int c = 0; c < 4; ++c)
#pragma unroll
            for (int r = 0; r < 4; ++r)
                Ps[w][quad * 4 + r][c * 16 + col_l] = f2b(pv[c][r]);
        bf16x8 pf0 = *(const bf16x8*)&Ps[w][col_l][quad * 8];
        bf16x8 pf1 = *(const bf16x8*)&Ps[w][col_l][32 + quad * 8];
#pragma unroll
        for (int ct = 0; ct < 8; ++ct) {
            bf16x8 v0 = *(const bf16x8*)&Vt[ct * 16 + col_l][quad * 8];
            bf16x8 v1 = *(const bf16x8*)&Vt[ct * 16 + col_l][32 + quad * 8];
            oacc[ct] = __builtin_amdgcn_mfma_f32_16x16x32_bf16(pf0, v0, oacc[ct], 0, 0, 0);
            oacc[ct] = __builtin_amdgcn_mfma_f32_16x16x32_bf16(pf1, v1, oacc[ct], 0, 0, 0);
        }
        __syncthreads();
    }

    // store unnormalized partials
    size_t slab = (size_t)(ks * 8 + bh) * NVP;
#pragma unroll
    for (int ct = 0; ct < 8; ++ct)
#pragma unroll
        for (int r = 0; r < 4; ++r) {
            int row = wq0 + quad * 4 + r;
            Opart[(slab + row) * HD + ct * 16 + col_l] = oacc[ct][r];
        }
    if (col_l == 0) {
#pragma unroll
        for (int r = 0; r < 4; ++r) {
            int row = wq0 + quad * 4 + r;
            ML[(slab + row) * 2 + 0] = m_run[r];
            ML[(slab + row) * 2 + 1] = l_run[r];
        }
    }
}

// ---------------------------------------------------------------- combine splits
// grid (588, 8): block = 2 rows x 128 d.
__global__ __launch_bounds__(256) void comb_kernel(const float* __restrict__ Opart,
                                                   const float* __restrict__ ML,
                                                   u16* __restrict__ Obuf) {
    int bh = blockIdx.y, b = bh >> 1, h = bh & 1;
    int tid = threadIdx.x;
    int row = blockIdx.x * 2 + (tid >> 7);
    int d = tid & 127;
    if (row >= NV) return;
    float m[KSPLIT], l[KSPLIT];
#pragma unroll
    for (int i = 0; i < KSPLIT; ++i) {
        size_t mb = ((size_t)(i * 8 + bh) * NVP + row) * 2;
        m[i] = ML[mb];
        l[i] = ML[mb + 1];
    }
    float M = m[0];
#pragma unroll
    for (int i = 1; i < KSPLIT; ++i) M = fmaxf(M, m[i]);
    float wsum = 0.f, o = 0.f;
#pragma unroll
    for (int i = 0; i < KSPLIT; ++i) {
        float wi = __expf(m[i] - M);
        wsum += l[i] * wi;
        o += Opart[((size_t)(i * 8 + bh) * NVP + row) * HD + d] * wi;
    }
    Obuf[((size_t)b * NV + row) * DMODEL + h * HD + d] = f2b(o / wsum);
}

// ---------------------------------------------------------------- residual + LN (+opt FFN2 prefill)
__global__ __launch_bounds__(256) void ln_kernel(const float* __restrict__ Xin,
                                                 const float* __restrict__ Res,
                                                 const float* __restrict__ w,
                                                 const float* __restrict__ bb,
                                                 float* __restrict__ Y,
                                                 u16* __restrict__ Yb,
                                                 const float* __restrict__ fb2,
                                                 float* __restrict__ A2out) {
    int r = blockIdx.x, d = threadIdx.x;
    size_t idx = (size_t)r * DMODEL + d;
    float v = Xin[idx];
    if (Res) v += Res[idx];
    float s1 = v, s2 = v * v;
#pragma unroll
    for (int off = 32; off > 0; off >>= 1) {
        s1 += __shfl_down(s1, off);
        s2 += __shfl_down(s2, off);
    }
    __shared__ float ps1[4], ps2[4];
    int wid = d >> 6, lane = d & 63;
    if (lane == 0) { ps1[wid] = s1; ps2[wid] = s2; }
    __syncthreads();
    if (d == 0) {
        ps1[0] = ps1[0] + ps1[1] + ps1[2] + ps1[3];
        ps2[0] = ps2[0] + ps2[1] + ps2[2] + ps2[3];
    }
    __syncthreads();
    float mean = ps1[0] * (1.f / DMODEL);
    float var = ps2[0] * (1.f / DMODEL) - mean * mean;
    float o = (v - mean) * rsqrtf(var + 1e-5f) * w[d] + bb[d];
    Y[idx] = o;
    Yb[idx] = f2b(o);
    if (A2out) A2out[idx] = o + fb2[d];   // FFN2 split-K prefill: X + bias
}

// ---------------------------------------------------------------- gather
__global__ __launch_bounds__(256) void gather_kernel(const float* __restrict__ Xf,
                                                     const int* __restrict__ s1,
                                                     const int* __restrict__ e1,
                                                     const int* __restrict__ qb,
                                                     const int* __restrict__ s2,
                                                     const int* __restrict__ e2,
                                                     float* __restrict__ out) {
    int q = blockIdx.x, which = blockIdx.y, d = threadIdx.x;
    int s = which ? s2[q] : s1[q];
    int e = which ? e2[q] : e1[q];
    int b = qb[q];
    int t = s * SEQ - (s * (s - 1)) / 2 + (e - s);
    if (t < 0) t = 0;
    if (t >= NV) t = NV - 1;
    out[((size_t)which * NQ_C + q) * DMODEL + d] = Xf[((size_t)b * NV + t) * DMODEL + d];
}

// ---------------------------------------------------------------- launch
extern "C" void kernel_launch(void* const* d_in, const int* in_sizes, int n_in,
                              void* d_out, int out_size, void* d_ws, size_t ws_size,
                              hipStream_t stream) {
    const float* enc = (const float*)d_in[0];
    const float* iw  = (const float*)d_in[1];
    const float* ib  = (const float*)d_in[2];
    const float* ow  = (const float*)d_in[3];
    const float* ob  = (const float*)d_in[4];
    const float* l1w = (const float*)d_in[5];
    const float* l1b = (const float*)d_in[6];
    const float* l2w = (const float*)d_in[7];
    const float* l2b = (const float*)d_in[8];
    const float* f1w = (const float*)d_in[9];
    const float* f1b = (const float*)d_in[10];
    const float* f2w = (const float*)d_in[11];
    const float* f2b_ = (const float*)d_in[12];
    const float* flw = (const float*)d_in[13];
    const float* flb = (const float*)d_in[14];
    const int* s1 = (const int*)d_in[15];
    const int* e1 = (const int*)d_in[16];
    const int* qb = (const int*)d_in[17];
    const int* s2 = (const int*)d_in[18];
    const int* e2 = (const int*)d_in[19];
    float* out = (float*)d_out;

    // ---------------- workspace layout (~50 MB) ----------------
    char* p = (char*)d_ws;
    float* X     = (float*)p;  p += (size_t)NTOT * DMODEL * 4;
    float* A2    = (float*)p;  p += (size_t)NTOT * DMODEL * 4;
    u16* Xb      = (u16*)p;    p += (size_t)NTOT * DMODEL * 2;
    u16* Obuf    = (u16*)p;    p += (size_t)NTOT * DMODEL * 2;
    u16* QKVb    = (u16*)p;    p += (size_t)NTOT * 3 * DMODEL * 2;
    u16* VT      = (u16*)p;    p += (size_t)8 * HD * NVP * 2;
    float* ML    = (float*)p;  p += (size_t)KSPLIT * 8 * NVP * 2 * 4;
    float* Opart = (float*)p;  p += (size_t)KSPLIT * 8 * NVP * HD * 4;
    u16* wb      = (u16*)p;
    u16* F1b     = (u16*)Opart;  // alias: FFN phase doesn't overlap attention phase
    float* Of    = A2;           // alias: final LN output

    u16* iwb  = wb;
    u16* owb  = iwb + 2 * 3 * DMODEL * DMODEL;
    u16* f1wb = owb + 2 * DMODEL * DMODEL;
    u16* f2wb = f1wb + 2 * DFF_C * DMODEL;

    castall_kernel<<<dim3(2560), 256, 0, stream>>>(iw, ow, f1w, f2w,
                                                   iwb, owb, f1wb, f2wb);
    span_kernel<<<dim3(SEQ, BSZ), 256, 0, stream>>>(enc, X, Xb);

    for (int l = 0; l < NLAYERS; ++l) {
        // QKV = Xb @ iw^T + ib -> bf16 [NTOT][768]
        mm_kernel<u16, false, false><<<dim3(12, 74, 1), 256, 0, stream>>>(
            Xb, iwb + (size_t)l * 3 * DMODEL * DMODEL, ib + (size_t)l * 3 * DMODEL,
            nullptr, QKVb, NTOT, DMODEL, DMODEL, DMODEL, 3 * DMODEL, 1.f,
            3 * DMODEL, DMODEL);
        // V^T per (b,h)
        vtrans_kernel<<<dim3(19, 2, 8), 256, 0, stream>>>(QKVb, VT);
        // flash-decoding attention partials + combine
        flash_kernel<<<dim3(19, 8, KSPLIT), 256, 0, stream>>>(QKVb, VT, Opart, ML);
        comb_kernel<<<dim3(588, 8), 256, 0, stream>>>(Opart, ML, Obuf);
        // A2 = X + Obuf @ ow^T + ob -> fp32 (residual fused)
        mm_kernel<float, false, false><<<dim3(4, 74, 1), 256, 0, stream>>>(
            Obuf, owb + (size_t)l * DMODEL * DMODEL, ob + (size_t)l * DMODEL,
            X, A2, NTOT, DMODEL, DMODEL, DMODEL, DMODEL, 1.f, DMODEL, DMODEL);
        // LN1 (+ prefill A2 = X + f2b for split-K FFN2)
        ln_kernel<<<dim3(NTOT), 256, 0, stream>>>(
            A2, nullptr, l1w + (size_t)l * DMODEL, l1b + (size_t)l * DMODEL,
            X, Xb, f2b_ + (size_t)l * DMODEL, A2);
        // F1 = relu(Xb @ f1w^T + f1b) -> bf16
        mm_kernel<u16, true, false><<<dim3(32, 74, 1), 256, 0, stream>>>(
            Xb, f1wb + (size_t)l * DFF_C * DMODEL, f1b + (size_t)l * DFF_C,
            nullptr, F1b, NTOT, DMODEL, DMODEL, DMODEL, DFF_C, 1.f, DFF_C, DMODEL);
        // A2 += F1 @ f2w^T (split-K x4, atomic)
        mm_kernel<float, false, true><<<dim3(4, 74, 4), 256, 0, stream>>>(
            F1b, f2wb + (size_t)l * DMODEL * DFF_C, nullptr, nullptr, A2,
            NTOT, DFF_C, DFF_C, DFF_C, DMODEL, 1.f, DMODEL, 512);
        ln_kernel<<<dim3(NTOT), 256, 0, stream>>>(
            A2, nullptr, l2w + (size_t)l * DMODEL, l2b + (size_t)l * DMODEL,
            X, Xb, nullptr, nullptr);
    }
    ln_kernel<<<dim3(NTOT), 256, 0, stream>>>(X, nullptr, flw, flb, Of, Xb,
                                              nullptr, nullptr);
    gather_kernel<<<dim3(NQ_C, 2), 256, 0, stream>>>(Of, s1, e1, qb, s2, e2, out);
}